// Round 2
// baseline (592.706 us; speedup 1.0000x reference)
//
#include <hip/hip_runtime.h>
#include <hip/hip_bf16.h>
#include <math.h>

// B=16, D=128, OUT=128, M runtime (100000).
// v2: kB redesigned for occupancy (512 thr / 8 waves, 24 waves/CU vs 12):
//   scores use relu(x)=(x+|x|)/2 split:
//     score = 0.5*[Σ np*w2 (per-m, hoisted) + Σ A*w2 (per-b const -> DROPPED:
//     softmax row-shift invariant) + Σ |np+A|*w2 (add + abs-fma = 2 ops/elem)]
//   pool partials -> fp32 atomicAdd into acc_g/lsum_acc (pacc + kC1 eliminated)
// kA: blocks 0-63 w1b=bf16(W1 node half); 64-71 anchor GEMM; 72 zero accumulators
// kDiv: out = acc/lsum

typedef __attribute__((ext_vector_type(8))) short bf16x8;
typedef __attribute__((ext_vector_type(4))) float f32x4;

__device__ __forceinline__ short f2bs(float f) {
    __hip_bfloat16 h = __float2bfloat16(f);
    return *reinterpret_cast<short*>(&h);
}
__device__ __forceinline__ float bs2f(ushort u) {
    union { unsigned int i; float f; } v; v.i = ((unsigned)u) << 16; return v.f;
}

__global__ __launch_bounds__(256) void kA(const float* __restrict__ W1,
                                          const float* __restrict__ xx,
                                          ushort* __restrict__ w1b,
                                          float* __restrict__ A,
                                          float* __restrict__ acc_g,
                                          float* __restrict__ lsum_acc) {
    const int bi = blockIdx.x, t = threadIdx.x;
    if (bi < 64) {
        int idx = bi * 256 + t;              // 16384 = 128o * 128d
        int o = idx >> 7, d = idx & 127;
        w1b[idx] = (ushort)f2bs(W1[o * 256 + 128 + d]);
        return;
    }
    if (bi == 72) {                          // zero fp32 accumulators
        for (int i = t; i < 2064; i += 256) {
            if (i < 2048) acc_g[i] = 0.f;
            else          lsum_acc[i - 2048] = 0.f;
        }
        return;
    }
    __shared__ float xxs[16 * 132];
    __shared__ float w1s[16 * 132];
    const int og0 = (bi - 64) * 16;
#pragma unroll
    for (int i = 0; i < 2; ++i) {
        int idx = t + 256 * i;               // 512 float4 = 16 rows * 32
        int r = idx >> 5, c4 = (idx & 31) << 2;
        *(float4*)&xxs[r * 132 + c4] = *(const float4*)&xx[r * 128 + c4];
        *(float4*)&w1s[r * 132 + c4] = *(const float4*)&W1[(og0 + r) * 256 + c4];
    }
    __syncthreads();
    const int ol = t >> 4, b = t & 15;
    float acc = 0.f;
#pragma unroll
    for (int d4 = 0; d4 < 32; ++d4) {
        float4 xv = *(float4*)&xxs[b * 132 + d4 * 4];
        float4 wv = *(float4*)&w1s[ol * 132 + d4 * 4];
        acc += xv.x * wv.x + xv.y * wv.y + xv.z * wv.z + xv.w * wv.w;
    }
    A[b * 128 + og0 + ol] = acc;
}

__global__ __launch_bounds__(512, 6) void kB(
    const float* __restrict__ in, const ushort* __restrict__ w1b,
    const float* __restrict__ W2, const float* __restrict__ A,
    float* __restrict__ acc_g, float* __restrict__ lsum_acc, int M) {
    __shared__ ushort ins[128 * 136];  // bf16 in-tile [m][d]
    __shared__ float As[16 * 128];     // A[b][o]
    __shared__ ushort pb[16 * 136];    // p bf16 [b][m(128)+pad]

    const int tid = threadIdx.x, bid = blockIdx.x;
    const int m0 = bid * 128;
    const int w = tid >> 6, lane = tid & 63;
    const int c = lane & 15, q = lane >> 4;
    const int lim = (M - m0 < 128) ? (M - m0) : 128;

    // ---- stage input tile -> LDS as bf16 (8 waves: 8 iters) ----
#pragma unroll
    for (int i = 0; i < 8; ++i) {
        int idx = tid + 512 * i;             // 4096 float4s = 128 rows * 32
        int r = idx >> 5, c4 = (idx & 31) << 2;
        float4 v = make_float4(0.f, 0.f, 0.f, 0.f);
        if (r < lim) v = *(const float4*)&in[(size_t)(m0 + r) * 128 + c4];
        ushort4 u;
        u.x = (ushort)f2bs(v.x); u.y = (ushort)f2bs(v.y);
        u.z = (ushort)f2bs(v.z); u.w = (ushort)f2bs(v.w);
        *(ushort4*)&ins[r * 136 + c4] = u;
    }
    // 2048 floats of A: one float4 per thread
    *(float4*)&As[tid * 4] = *(const float4*)&A[tid * 4];
    __syncthreads();

    // ---- np^T via MFMA: wave w owns m-tile w (m = w*16 + c) ----
    const int mbase = w * 16 + c;
    f32x4 acc[8];
#pragma unroll
    for (int ot = 0; ot < 8; ++ot) acc[ot] = (f32x4){0.f, 0.f, 0.f, 0.f};
#pragma unroll
    for (int kb = 0; kb < 4; ++kb) {
        bf16x8 bv = *(const bf16x8*)&ins[mbase * 136 + kb * 32 + q * 8];
#pragma unroll
        for (int ot = 0; ot < 8; ++ot) {
            bf16x8 av = *(const bf16x8*)(w1b + (ot * 16 + c) * 128 + kb * 32 + q * 8);
            acc[ot] = __builtin_amdgcn_mfma_f32_16x16x32_bf16(av, bv, acc[ot], 0, 0, 0);
        }
    }
    // acc[ot][r] = np[m = w*16 + c][o = ot*16 + q*4 + r]

    // ---- scores: sa[b] = 0.5*Sum_o |np+A|*w2 ; sm = 0.5*Sum_o np*w2 ----
    // (per-b constant 0.5*Sum A*w2 dropped: softmax invariant to row shifts)
    const bool mv = (w * 16 + c) < lim;
    float sa[16];
#pragma unroll
    for (int b = 0; b < 16; ++b) sa[b] = 0.f;
    float sm = 0.f;
#pragma unroll
    for (int ot = 0; ot < 8; ++ot) {
        f32x4 wq = *(const f32x4*)&W2[ot * 16 + q * 4];
        wq *= 0.5f;
#pragma unroll
        for (int r = 0; r < 4; ++r) sm += acc[ot][r] * wq[r];
#pragma unroll
        for (int b = 0; b < 16; ++b) {
            f32x4 aq = *(f32x4*)&As[b * 128 + ot * 16 + q * 4];  // 16-lane broadcast
#pragma unroll
            for (int r = 0; r < 4; ++r)
                sa[b] += fabsf(acc[ot][r] + aq[r]) * wq[r];      // abs folds into fma
        }
    }
#pragma unroll
    for (int b = 0; b < 16; ++b) {
        float s = sa[b] + sm;
        s += __shfl_xor(s, 16, 64);
        s += __shfl_xor(s, 32, 64);
        if (q == (b & 3))
            pb[b * 136 + w * 16 + c] = (ushort)f2bs(mv ? __expf(s) : 0.f);
    }
    __syncthreads();

    // ---- pool via MFMA: wave w owns d-tile w; fp32 atomic accumulate ----
    const int dloc = w * 16 + c;
    f32x4 pd = (f32x4){0.f, 0.f, 0.f, 0.f};
#pragma unroll
    for (int ks = 0; ks < 4; ++ks) {
        bf16x8 pf = *(const bf16x8*)&pb[c * 136 + ks * 32 + q * 8];  // A-frag P[b=c][k]
        bf16x8 bf;
#pragma unroll
        for (int j = 0; j < 8; ++j)
            bf[j] = (short)ins[(ks * 32 + q * 8 + j) * 136 + dloc];
        pd = __builtin_amdgcn_mfma_f32_16x16x32_bf16(pf, bf, pd, 0, 0, 0);
    }
    // pd[r] = pool[b = q*4+r][d = dloc]
#pragma unroll
    for (int r = 0; r < 4; ++r)
        atomicAdd(&acc_g[(q * 4 + r) * 128 + dloc], pd[r]);

    // ---- block lsum: thread (b = tid>>5, jj = tid&31) covers 4 m each ----
    {
        const int bb = tid >> 5, jj = tid & 31;
        const ushort* pr = &pb[bb * 136 + jj * 4];
        float part = 0.f;
#pragma unroll
        for (int j2 = 0; j2 < 4; ++j2) part += bs2f(pr[j2]);
#pragma unroll
        for (int off = 1; off < 32; off <<= 1) part += __shfl_xor(part, off, 64);
        if (jj == 0) atomicAdd(&lsum_acc[bb], part);
    }
}

__global__ void kDiv(const float* __restrict__ acc_g,
                     const float* __restrict__ lsum_acc,
                     float* __restrict__ out) {
    const int b = blockIdx.x, t = threadIdx.x;   // 16 blocks x 128 threads
    out[b * 128 + t] = acc_g[b * 128 + t] / lsum_acc[b];
}

extern "C" void kernel_launch(void* const* d_in, const int* in_sizes, int n_in,
                              void* d_out, int out_size, void* d_ws, size_t ws_size,
                              hipStream_t stream) {
    const float* xx = (const float*)d_in[0];
    const float* in = (const float*)d_in[1];
    // d_in[2] = adj, unused
    const float* W1 = (const float*)d_in[3];
    const float* W2 = (const float*)d_in[4];
    float* out = (float*)d_out;

    const int M = in_sizes[1] / 128;
    const int nb = (M + 127) / 128;

    float* ws = (float*)d_ws;
    float* A        = ws;                    // 2048
    float* acc_g    = A + 2048;              // 2048
    float* lsum_acc = acc_g + 2048;          // 16
    ushort* w1b     = (ushort*)(lsum_acc + 16); // 16384 bf16 (16B-aligned: 16448/16)

    kA  <<<73, 256, 0, stream>>>(W1, xx, w1b, A, acc_g, lsum_acc);
    kB  <<<nb, 512, 0, stream>>>(in, w1b, W2, A, acc_g, lsum_acc, M);
    kDiv<<<16, 128, 0, stream>>>(acc_g, lsum_acc, out);
}

// Round 3
// 468.732 us; speedup vs baseline: 1.2645x; 1.2645x over previous
//
#include <hip/hip_runtime.h>
#include <hip/hip_bf16.h>
#include <math.h>

// B=16, D=128, OUT=128, M runtime (100000).
// v3: v2's math (HW-verified correct) with spill-safe scheduling:
//   - kB: 64-row tiles, 256 thr / 4 waves, LDS 27.9KB -> 5 blocks/CU (20 waves)
//   - __launch_bounds__(256,4): VGPR cap 128, demand ~70 -> no spill
//     (v2 lesson: tight cap + MFMA accumulators => compiler spills to scratch)
//   - scores: relu(x)=(x+|x|)/2 split; per-b const dropped (softmax shift-inv)
//   - pool -> fp32 atomicAdd into acc_g/lsum_acc
// kA: blocks 0-63 w1b=bf16(W1 node half); 64-71 anchor GEMM; 72 zero accumulators
// kDiv: out = acc/lsum

typedef __attribute__((ext_vector_type(8))) short bf16x8;
typedef __attribute__((ext_vector_type(4))) float f32x4;

__device__ __forceinline__ short f2bs(float f) {
    __hip_bfloat16 h = __float2bfloat16(f);
    return *reinterpret_cast<short*>(&h);
}
__device__ __forceinline__ float bs2f(ushort u) {
    union { unsigned int i; float f; } v; v.i = ((unsigned)u) << 16; return v.f;
}

__global__ __launch_bounds__(256) void kA(const float* __restrict__ W1,
                                          const float* __restrict__ xx,
                                          ushort* __restrict__ w1b,
                                          float* __restrict__ A,
                                          float* __restrict__ acc_g,
                                          float* __restrict__ lsum_acc) {
    const int bi = blockIdx.x, t = threadIdx.x;
    if (bi < 64) {
        int idx = bi * 256 + t;              // 16384 = 128o * 128d
        int o = idx >> 7, d = idx & 127;
        w1b[idx] = (ushort)f2bs(W1[o * 256 + 128 + d]);
        return;
    }
    if (bi == 72) {                          // zero fp32 accumulators
        for (int i = t; i < 2064; i += 256) {
            if (i < 2048) acc_g[i] = 0.f;
            else          lsum_acc[i - 2048] = 0.f;
        }
        return;
    }
    __shared__ float xxs[16 * 132];
    __shared__ float w1s[16 * 132];
    const int og0 = (bi - 64) * 16;
#pragma unroll
    for (int i = 0; i < 2; ++i) {
        int idx = t + 256 * i;               // 512 float4 = 16 rows * 32
        int r = idx >> 5, c4 = (idx & 31) << 2;
        *(float4*)&xxs[r * 132 + c4] = *(const float4*)&xx[r * 128 + c4];
        *(float4*)&w1s[r * 132 + c4] = *(const float4*)&W1[(og0 + r) * 256 + c4];
    }
    __syncthreads();
    const int ol = t >> 4, b = t & 15;
    float acc = 0.f;
#pragma unroll
    for (int d4 = 0; d4 < 32; ++d4) {
        float4 xv = *(float4*)&xxs[b * 132 + d4 * 4];
        float4 wv = *(float4*)&w1s[ol * 132 + d4 * 4];
        acc += xv.x * wv.x + xv.y * wv.y + xv.z * wv.z + xv.w * wv.w;
    }
    A[b * 128 + og0 + ol] = acc;
}

__global__ __launch_bounds__(256, 4) void kB(
    const float* __restrict__ in, const ushort* __restrict__ w1b,
    const float* __restrict__ W2, const float* __restrict__ A,
    float* __restrict__ acc_g, float* __restrict__ lsum_acc, int M) {
    __shared__ ushort ins[64 * 136];   // bf16 in-tile [m][d], 17408 B
    __shared__ float As[16 * 128];     // A[b][o], 8192 B
    __shared__ ushort pb[16 * 72];     // p bf16 [b][m(64)+pad8], 2304 B

    const int tid = threadIdx.x, bid = blockIdx.x;
    const int m0 = bid * 64;
    const int w = tid >> 6, lane = tid & 63;
    const int c = lane & 15, q = lane >> 4;
    const int lim = (M - m0 < 64) ? (M - m0) : 64;

    // ---- stage input tile -> LDS as bf16: 2048 float4 = 64 rows * 32 ----
#pragma unroll
    for (int i = 0; i < 8; ++i) {
        int idx = tid + 256 * i;
        int r = idx >> 5, c4 = (idx & 31) << 2;
        float4 v = make_float4(0.f, 0.f, 0.f, 0.f);
        if (r < lim) v = *(const float4*)&in[(size_t)(m0 + r) * 128 + c4];
        ushort4 u;
        u.x = (ushort)f2bs(v.x); u.y = (ushort)f2bs(v.y);
        u.z = (ushort)f2bs(v.z); u.w = (ushort)f2bs(v.w);
        *(ushort4*)&ins[r * 136 + c4] = u;
    }
    // 2048 floats of A: two float4 per thread
#pragma unroll
    for (int i = 0; i < 2; ++i) {
        int idx = tid + 256 * i;
        *(float4*)&As[idx * 4] = *(const float4*)&A[idx * 4];
    }
    __syncthreads();

    // ---- np^T via MFMA: wave w owns m-tile w (m = w*16 + c) ----
    const int mbase = w * 16 + c;
    f32x4 acc[8];
#pragma unroll
    for (int ot = 0; ot < 8; ++ot) acc[ot] = (f32x4){0.f, 0.f, 0.f, 0.f};
#pragma unroll
    for (int kb = 0; kb < 4; ++kb) {
        bf16x8 bv = *(const bf16x8*)&ins[mbase * 136 + kb * 32 + q * 8];
#pragma unroll
        for (int ot = 0; ot < 8; ++ot) {
            bf16x8 av = *(const bf16x8*)(w1b + (ot * 16 + c) * 128 + kb * 32 + q * 8);
            acc[ot] = __builtin_amdgcn_mfma_f32_16x16x32_bf16(av, bv, acc[ot], 0, 0, 0);
        }
    }
    // acc[ot][r] = np[m = w*16 + c][o = ot*16 + q*4 + r]

    // ---- scores: sa[b] = 0.5*Sum_o |np+A|*w2 ; sm = 0.5*Sum_o np*w2 ----
    // (per-b constant 0.5*Sum A*w2 dropped: softmax invariant to row shifts)
    const bool mv = (w * 16 + c) < lim;
    float sa[16];
#pragma unroll
    for (int b = 0; b < 16; ++b) sa[b] = 0.f;
    float sm = 0.f;
#pragma unroll
    for (int ot = 0; ot < 8; ++ot) {
        f32x4 wq = *(const f32x4*)&W2[ot * 16 + q * 4];
        wq *= 0.5f;
#pragma unroll
        for (int r = 0; r < 4; ++r) sm += acc[ot][r] * wq[r];
#pragma unroll
        for (int b = 0; b < 16; ++b) {
            f32x4 aq = *(f32x4*)&As[b * 128 + ot * 16 + q * 4];  // 16-lane broadcast
#pragma unroll
            for (int r = 0; r < 4; ++r)
                sa[b] += fabsf(acc[ot][r] + aq[r]) * wq[r];      // abs folds into fma
        }
    }
#pragma unroll
    for (int b = 0; b < 16; ++b) {
        float s = sa[b] + sm;
        s += __shfl_xor(s, 16, 64);
        s += __shfl_xor(s, 32, 64);
        if (q == (b & 3))
            pb[b * 72 + w * 16 + c] = (ushort)f2bs(mv ? __expf(s) : 0.f);
    }
    __syncthreads();

    // ---- pool via MFMA: D = P[16b x 64m] . in[64m x 128d]; wave owns 32 d ----
    f32x4 pd[2];
    pd[0] = (f32x4){0.f, 0.f, 0.f, 0.f};
    pd[1] = (f32x4){0.f, 0.f, 0.f, 0.f};
#pragma unroll
    for (int ks = 0; ks < 2; ++ks) {
        bf16x8 pf = *(const bf16x8*)&pb[c * 72 + ks * 32 + q * 8];  // A-frag P[b=c][k]
#pragma unroll
        for (int t = 0; t < 2; ++t) {
            const int dloc = w * 32 + t * 16 + c;
            bf16x8 bf;
#pragma unroll
            for (int j = 0; j < 8; ++j)
                bf[j] = (short)ins[(ks * 32 + q * 8 + j) * 136 + dloc];
            pd[t] = __builtin_amdgcn_mfma_f32_16x16x32_bf16(pf, bf, pd[t], 0, 0, 0);
        }
    }
    // pd[t][r] = pool[b = q*4+r][d = w*32 + t*16 + c]
#pragma unroll
    for (int t = 0; t < 2; ++t)
#pragma unroll
        for (int r = 0; r < 4; ++r)
            atomicAdd(&acc_g[(q * 4 + r) * 128 + w * 32 + t * 16 + c], pd[t][r]);

    // ---- block lsum: thread (b = tid>>4, jj = tid&15) covers 4 m each ----
    {
        const int bb = tid >> 4, jj = tid & 15;
        const ushort* pr = &pb[bb * 72 + jj * 4];
        float part = 0.f;
#pragma unroll
        for (int j2 = 0; j2 < 4; ++j2) part += bs2f(pr[j2]);
#pragma unroll
        for (int off = 1; off < 16; off <<= 1) part += __shfl_xor(part, off, 64);
        if (jj == 0) atomicAdd(&lsum_acc[bb], part);
    }
}

__global__ void kDiv(const float* __restrict__ acc_g,
                     const float* __restrict__ lsum_acc,
                     float* __restrict__ out) {
    const int b = blockIdx.x, t = threadIdx.x;   // 16 blocks x 128 threads
    out[b * 128 + t] = acc_g[b * 128 + t] / lsum_acc[b];
}

extern "C" void kernel_launch(void* const* d_in, const int* in_sizes, int n_in,
                              void* d_out, int out_size, void* d_ws, size_t ws_size,
                              hipStream_t stream) {
    const float* xx = (const float*)d_in[0];
    const float* in = (const float*)d_in[1];
    // d_in[2] = adj, unused
    const float* W1 = (const float*)d_in[3];
    const float* W2 = (const float*)d_in[4];
    float* out = (float*)d_out;

    const int M = in_sizes[1] / 128;
    const int nb = (M + 63) / 64;

    float* ws = (float*)d_ws;
    float* A        = ws;                    // 2048
    float* acc_g    = A + 2048;              // 2048
    float* lsum_acc = acc_g + 2048;          // 16
    ushort* w1b     = (ushort*)(lsum_acc + 16); // 16384 bf16 (16B-aligned)

    kA  <<<73, 256, 0, stream>>>(W1, xx, w1b, A, acc_g, lsum_acc);
    kB  <<<nb, 256, 0, stream>>>(in, w1b, W2, A, acc_g, lsum_acc, M);
    kDiv<<<16, 128, 0, stream>>>(acc_g, lsum_acc, out);
}

// Round 4
// 197.621 us; speedup vs baseline: 2.9992x; 2.3719x over previous
//
#include <hip/hip_runtime.h>
#include <hip/hip_bf16.h>
#include <math.h>

// B=16, D=128, OUT=128, M runtime (100000).
// v4: v1's proven non-spilling loop structure + v2's verified math + occupancy:
//   - kB: 512 thr / 8 waves, 128-row tile, ONE 16-row m-tile per wave
//     (acc[8] = 32 regs vs v1's 64; v2/v3 lesson: the sa[16] accumulator array
//      spilled to scratch -> ~1 GB phantom HBM traffic. b-outer + scalar sab.)
//   - scores: relu(x)=(x+|x|)/2 split; sm = 0.5*Sum np*w2 hoisted (b-invariant);
//     per-b const dropped (softmax shift-inv); 0.5 pre-folded into w2s in LDS
//   - pool -> fp32 atomicAdd into acc_g/lsum_acc (no pacc/kC1 round trip)
// kA: blocks 0-63 w1b=bf16(W1 node half); 64-71 anchor GEMM; 72 zero accumulators
// kDiv: out = acc/lsum

typedef __attribute__((ext_vector_type(8))) short bf16x8;
typedef __attribute__((ext_vector_type(4))) float f32x4;

__device__ __forceinline__ short f2bs(float f) {
    __hip_bfloat16 h = __float2bfloat16(f);
    return *reinterpret_cast<short*>(&h);
}
__device__ __forceinline__ float bs2f(ushort u) {
    union { unsigned int i; float f; } v; v.i = ((unsigned)u) << 16; return v.f;
}

__global__ __launch_bounds__(256) void kA(const float* __restrict__ W1,
                                          const float* __restrict__ xx,
                                          ushort* __restrict__ w1b,
                                          float* __restrict__ A,
                                          float* __restrict__ acc_g,
                                          float* __restrict__ lsum_acc) {
    const int bi = blockIdx.x, t = threadIdx.x;
    if (bi < 64) {
        int idx = bi * 256 + t;              // 16384 = 128o * 128d
        int o = idx >> 7, d = idx & 127;
        w1b[idx] = (ushort)f2bs(W1[o * 256 + 128 + d]);
        return;
    }
    if (bi == 72) {                          // zero fp32 accumulators
        for (int i = t; i < 2064; i += 256) {
            if (i < 2048) acc_g[i] = 0.f;
            else          lsum_acc[i - 2048] = 0.f;
        }
        return;
    }
    __shared__ float xxs[16 * 132];
    __shared__ float w1s[16 * 132];
    const int og0 = (bi - 64) * 16;
#pragma unroll
    for (int i = 0; i < 2; ++i) {
        int idx = t + 256 * i;               // 512 float4 = 16 rows * 32
        int r = idx >> 5, c4 = (idx & 31) << 2;
        *(float4*)&xxs[r * 132 + c4] = *(const float4*)&xx[r * 128 + c4];
        *(float4*)&w1s[r * 132 + c4] = *(const float4*)&W1[(og0 + r) * 256 + c4];
    }
    __syncthreads();
    const int ol = t >> 4, b = t & 15;
    float acc = 0.f;
#pragma unroll
    for (int d4 = 0; d4 < 32; ++d4) {
        float4 xv = *(float4*)&xxs[b * 132 + d4 * 4];
        float4 wv = *(float4*)&w1s[ol * 132 + d4 * 4];
        acc += xv.x * wv.x + xv.y * wv.y + xv.z * wv.z + xv.w * wv.w;
    }
    A[b * 128 + og0 + ol] = acc;
}

__global__ __launch_bounds__(512, 2) void kB(
    const float* __restrict__ in, const ushort* __restrict__ w1b,
    const float* __restrict__ W2, const float* __restrict__ A,
    float* __restrict__ acc_g, float* __restrict__ lsum_acc, int M) {
    __shared__ ushort ins[128 * 136];  // bf16 in-tile [m][d], 34816 B
    __shared__ float As[16 * 128];     // A[b][o], 8192 B
    __shared__ float w2s[128];         // 0.5*W2, 512 B
    __shared__ ushort pb[16 * 136];    // p bf16 [b][m(128)+pad], 4352 B

    const int tid = threadIdx.x, bid = blockIdx.x;
    const int m0 = bid * 128;
    const int w = tid >> 6, lane = tid & 63;
    const int c = lane & 15, q = lane >> 4;
    const int lim = (M - m0 < 128) ? (M - m0) : 128;

    // ---- stage input tile -> LDS as bf16: 4096 float4 = 128 rows * 32 ----
#pragma unroll
    for (int i = 0; i < 8; ++i) {
        int idx = tid + 512 * i;
        int r = idx >> 5, c4 = (idx & 31) << 2;
        float4 v = make_float4(0.f, 0.f, 0.f, 0.f);
        if (r < lim) v = *(const float4*)&in[(size_t)(m0 + r) * 128 + c4];
        ushort4 u;
        u.x = (ushort)f2bs(v.x); u.y = (ushort)f2bs(v.y);
        u.z = (ushort)f2bs(v.z); u.w = (ushort)f2bs(v.w);
        *(ushort4*)&ins[r * 136 + c4] = u;
    }
    // 2048 floats of A: one float4 per thread
    *(float4*)&As[tid * 4] = *(const float4*)&A[tid * 4];
    if (tid < 128) w2s[tid] = 0.5f * W2[tid];
    __syncthreads();

    // ---- np^T via MFMA: wave w owns m-tile w (m = w*16 + c) ----
    const int mbase = w * 16 + c;
    f32x4 acc[8];
#pragma unroll
    for (int ot = 0; ot < 8; ++ot) acc[ot] = (f32x4){0.f, 0.f, 0.f, 0.f};
#pragma unroll
    for (int kb = 0; kb < 4; ++kb) {
        bf16x8 bv = *(const bf16x8*)&ins[mbase * 136 + kb * 32 + q * 8];
#pragma unroll
        for (int ot = 0; ot < 8; ++ot) {
            bf16x8 av = *(const bf16x8*)(w1b + (ot * 16 + c) * 128 + kb * 32 + q * 8);
            acc[ot] = __builtin_amdgcn_mfma_f32_16x16x32_bf16(av, bv, acc[ot], 0, 0, 0);
        }
    }
    // acc[ot][r] = np[m = w*16 + c][o = ot*16 + q*4 + r]

    // ---- sm = 0.5*Sum_o np*w2 (b-invariant, hoisted) ----
    float sm = 0.f;
#pragma unroll
    for (int ot = 0; ot < 8; ++ot) {
        f32x4 wq = *(f32x4*)&w2s[ot * 16 + q * 4];
#pragma unroll
        for (int r = 0; r < 4; ++r) sm += acc[ot][r] * wq[r];
    }

    // ---- scores: b-outer, SCALAR accumulator (spill-proof structure) ----
    // s(b) = sm + 0.5*Sum_o |np+A|*w2   (per-b const dropped: softmax shift-inv)
    const bool mv = mbase < lim;
    for (int b = 0; b < 16; ++b) {
        float sab = 0.f;
#pragma unroll
        for (int ot = 0; ot < 8; ++ot) {
            f32x4 aq = *(f32x4*)&As[b * 128 + ot * 16 + q * 4];  // 16-lane broadcast
            f32x4 wq = *(f32x4*)&w2s[ot * 16 + q * 4];
#pragma unroll
            for (int r = 0; r < 4; ++r)
                sab += fabsf(acc[ot][r] + aq[r]) * wq[r];        // abs is free modifier
        }
        float s = sab + sm;
        s += __shfl_xor(s, 16, 64);
        s += __shfl_xor(s, 32, 64);
        if (q == (b & 3))
            pb[b * 136 + w * 16 + c] = (ushort)f2bs(mv ? __expf(s) : 0.f);
    }
    __syncthreads();

    // ---- pool via MFMA: D = P[16b x 128m] . in[128m x 128d]; wave owns 16 d ----
    const int dloc = w * 16 + c;
    f32x4 pd = (f32x4){0.f, 0.f, 0.f, 0.f};
#pragma unroll
    for (int ks = 0; ks < 4; ++ks) {
        bf16x8 pf = *(const bf16x8*)&pb[c * 136 + ks * 32 + q * 8];  // A-frag P[b=c][k]
        bf16x8 bf;
#pragma unroll
        for (int j = 0; j < 8; ++j)
            bf[j] = (short)ins[(ks * 32 + q * 8 + j) * 136 + dloc];
        pd = __builtin_amdgcn_mfma_f32_16x16x32_bf16(pf, bf, pd, 0, 0, 0);
    }
    // pd[r] = pool[b = q*4+r][d = dloc]
#pragma unroll
    for (int r = 0; r < 4; ++r)
        atomicAdd(&acc_g[(q * 4 + r) * 128 + dloc], pd[r]);

    // ---- block lsum: thread (b = tid>>5, jj = tid&31) covers 4 m each ----
    {
        const int bb = tid >> 5, jj = tid & 31;
        const ushort* pr = &pb[bb * 136 + jj * 4];
        float part = 0.f;
#pragma unroll
        for (int j2 = 0; j2 < 4; ++j2) part += bs2f(pr[j2]);
#pragma unroll
        for (int off = 1; off < 32; off <<= 1) part += __shfl_xor(part, off, 64);
        if (jj == 0) atomicAdd(&lsum_acc[bb], part);
    }
}

__global__ void kDiv(const float* __restrict__ acc_g,
                     const float* __restrict__ lsum_acc,
                     float* __restrict__ out) {
    const int b = blockIdx.x, t = threadIdx.x;   // 16 blocks x 128 threads
    out[b * 128 + t] = acc_g[b * 128 + t] / lsum_acc[b];
}

extern "C" void kernel_launch(void* const* d_in, const int* in_sizes, int n_in,
                              void* d_out, int out_size, void* d_ws, size_t ws_size,
                              hipStream_t stream) {
    const float* xx = (const float*)d_in[0];
    const float* in = (const float*)d_in[1];
    // d_in[2] = adj, unused
    const float* W1 = (const float*)d_in[3];
    const float* W2 = (const float*)d_in[4];
    float* out = (float*)d_out;

    const int M = in_sizes[1] / 128;
    const int nb = (M + 127) / 128;

    float* ws = (float*)d_ws;
    float* A        = ws;                    // 2048
    float* acc_g    = A + 2048;              // 2048
    float* lsum_acc = acc_g + 2048;          // 16
    ushort* w1b     = (ushort*)(lsum_acc + 16); // 16384 bf16 (16B-aligned)

    kA  <<<73, 256, 0, stream>>>(W1, xx, w1b, A, acc_g, lsum_acc);
    kB  <<<nb, 512, 0, stream>>>(in, w1b, W2, A, acc_g, lsum_acc, M);
    kDiv<<<16, 128, 0, stream>>>(acc_g, lsum_acc, out);
}